// Round 3
// baseline (302.406 us; speedup 1.0000x reference)
//
#include <hip/hip_runtime.h>
#include <math.h>

#define B_   32
#define N_   128
#define H_   100
#define VT   4          // v rows per block
#define TPB  256        // 4 waves; threads (v in 0..3, hp in 0..49) -> 200 active
#define ROWS (B_ * N_)  // 4096

// ---------------------------------------------------------------------------
// K0: per-edge mask as float (0/1) + per-node mask. One wave per row.
__global__ __launch_bounds__(256) void k_mask(const float* __restrict__ edges,
                                              float* __restrict__ maskf,
                                              float* __restrict__ nmask) {
    const int t = threadIdx.x, lane = t & 63, wv = t >> 6;
    const int row = blockIdx.x * 4 + wv;
    const float4* eg = (const float4*)(edges + (size_t)row * N_ * 4);
    const float4 e0 = eg[lane], e1 = eg[lane + 64];
    const float s0 = (e0.x + e0.y) + (e0.z + e0.w);
    const float s1 = (e1.x + e1.y) + (e1.z + e1.w);
    maskf[(size_t)row * N_ + lane]      = (s0 != 0.f) ? 1.f : 0.f;
    maskf[(size_t)row * N_ + 64 + lane] = (s1 != 0.f) ? 1.f : 0.f;
    const unsigned long long bl = __ballot((s0 != 0.f) || (s1 != 0.f));
    if (lane == 0) nmask[row] = bl ? 1.f : 0.f;
}

// ---------------------------------------------------------------------------
// K1: initial projections hv = nodes@Wv, hw = nodes@Ww
__global__ __launch_bounds__(TPB) void k_proj0(const float* __restrict__ nodes,
                                               const float* __restrict__ Wv,
                                               const float* __restrict__ Ww,
                                               float* __restrict__ hv_out,
                                               float* __restrict__ hw_out) {
    __shared__ float hid_s[VT * H_];
    const int b = blockIdx.y, v0 = blockIdx.x * VT;
    const int t = threadIdx.x, v = t / 50, hp = t % 50;
    const bool act = (v < VT);
    const int row = b * N_ + v0 + (act ? v : 0);

    const float4* ng = (const float4*)(nodes + (size_t)(b * N_ + v0) * H_);
    for (int idx = t; idx < VT * 25; idx += TPB) ((float4*)hid_s)[idx] = ng[idx];
    __syncthreads();
    if (!act) return;

    const float2* Wv2 = (const float2*)Wv;
    const float2* Ww2 = (const float2*)Ww;
    float va0 = 0, va1 = 0, wa0 = 0, wa1 = 0;
    const float* hr = hid_s + v * H_;
#pragma unroll 4
    for (int k = 0; k < H_; ++k) {
        const float hk = hr[k];
        const float2 wv = Wv2[k * 50 + hp];
        const float2 ww = Ww2[k * 50 + hp];
        va0 = fmaf(hk, wv.x, va0); va1 = fmaf(hk, wv.y, va1);
        wa0 = fmaf(hk, ww.x, wa0); wa1 = fmaf(hk, ww.y, wa1);
    }
    *(float2*)(hv_out + (size_t)row * H_ + hp * 2) = make_float2(va0, va1);
    *(float2*)(hw_out + (size_t)row * H_ + hp * 2) = make_float2(wa0, wa1);
}

// ---------------------------------------------------------------------------
// K2: one fused message pass.
//   messages: LDS-staged hw (two 64-w halves), edges straight from global
//   (per-(v,w) float4 is lane-broadcast, block's 8KB edge rows are L1-hot),
//   mask from precomputed maskf staged in LDS.
//   Then tanh update + (optionally) next pass's hv/hw projections.
// hv is block-private across passes; hw is double-buffered (crosses blocks).
__global__ __launch_bounds__(TPB) void k_pass(const float* __restrict__ edges,
                                              const float* __restrict__ maskf,
                                              const float* __restrict__ Wv,
                                              const float* __restrict__ Ww,
                                              const float* __restrict__ We,
                                              const float* __restrict__ Wu,
                                              float* hv_io,
                                              const float* __restrict__ hw_in,
                                              float* __restrict__ hw_out,
                                              const float* hid_in,
                                              float* hidden,
                                              const float* __restrict__ nmask,
                                              int do_proj) {
    __shared__ float hw_s[64 * H_];     // 25.6 KB
    __shared__ float hid_s[VT * H_];    // 1.6 KB (pre-update hidden rows)
    __shared__ float msg_s[VT * H_];    // 1.6 KB
    __shared__ float hnew_s[VT * H_];   // 1.6 KB
    __shared__ float mask_s[VT * N_];   // 2.0 KB

    const int b = blockIdx.y, v0 = blockIdx.x * VT;
    const int t = threadIdx.x, v = t / 50, hp = t % 50;
    const bool act = (v < VT);
    const int row = b * N_ + v0 + (act ? v : 0);

    float2 hv2 = make_float2(0.f, 0.f), we0, we1, we2, we3;
    if (act) {
        hv2 = *(const float2*)(hv_io + (size_t)row * H_ + hp * 2);
        we0 = *(const float2*)(We + 0 * H_ + hp * 2);
        we1 = *(const float2*)(We + 1 * H_ + hp * 2);
        we2 = *(const float2*)(We + 2 * H_ + hp * 2);
        we3 = *(const float2*)(We + 3 * H_ + hp * 2);
    }
    const float4* ev = (const float4*)edges + (size_t)(b * N_ + v0 + (act ? v : 0)) * N_;

    // stage: own hidden rows, own mask rows, hw half 0
    {
        const float4* hg = (const float4*)(hid_in + (size_t)(b * N_ + v0) * H_);
        for (int idx = t; idx < VT * 25; idx += TPB) ((float4*)hid_s)[idx] = hg[idx];
        const float4* mg = (const float4*)(maskf + (size_t)(b * N_ + v0) * N_);
        for (int idx = t; idx < VT * 32; idx += TPB) ((float4*)mask_s)[idx] = mg[idx];
        const float4* hwg = (const float4*)(hw_in + (size_t)b * N_ * H_);
        for (int idx = t; idx < 1600; idx += TPB) ((float4*)hw_s)[idx] = hwg[idx];
    }
    __syncthreads();

    float a0 = 0.f, a1 = 0.f;
    if (act) {
        const float* mv = mask_s + v * N_;
#pragma unroll 8
        for (int w = 0; w < 64; ++w) {
            const float4 e = ev[w];
            const float  m = mv[w];
            const float2 hw2 = *(const float2*)(hw_s + w * H_ + hp * 2);
            float p0 = hv2.x + hw2.x, p1 = hv2.y + hw2.y;
            p0 = fmaf(e.x, we0.x, p0); p1 = fmaf(e.x, we0.y, p1);
            p0 = fmaf(e.y, we1.x, p0); p1 = fmaf(e.y, we1.y, p1);
            p0 = fmaf(e.z, we2.x, p0); p1 = fmaf(e.z, we2.y, p1);
            p0 = fmaf(e.w, we3.x, p0); p1 = fmaf(e.w, we3.y, p1);
            a0 = fmaf(m, fmaxf(p0, 0.f), a0);
            a1 = fmaf(m, fmaxf(p1, 0.f), a1);
        }
    }
    __syncthreads();    // half-0 reads done
    {   // stage hw half 1
        const float4* hwg = (const float4*)(hw_in + (size_t)(b * N_ + 64) * H_);
        for (int idx = t; idx < 1600; idx += TPB) ((float4*)hw_s)[idx] = hwg[idx];
    }
    __syncthreads();
    if (act) {
        const float* mv = mask_s + v * N_ + 64;
        const float4* ev1 = ev + 64;
#pragma unroll 8
        for (int w = 0; w < 64; ++w) {
            const float4 e = ev1[w];
            const float  m = mv[w];
            const float2 hw2 = *(const float2*)(hw_s + w * H_ + hp * 2);
            float p0 = hv2.x + hw2.x, p1 = hv2.y + hw2.y;
            p0 = fmaf(e.x, we0.x, p0); p1 = fmaf(e.x, we0.y, p1);
            p0 = fmaf(e.y, we1.x, p0); p1 = fmaf(e.y, we1.y, p1);
            p0 = fmaf(e.z, we2.x, p0); p1 = fmaf(e.z, we2.y, p1);
            p0 = fmaf(e.w, we3.x, p0); p1 = fmaf(e.w, we3.y, p1);
            a0 = fmaf(m, fmaxf(p0, 0.f), a0);
            a1 = fmaf(m, fmaxf(p1, 0.f), a1);
        }
        *(float2*)(msg_s + v * H_ + hp * 2) = make_float2(a0, a1);
    }
    __syncthreads();    // msg visible

    // update: u = [hid, msg] @ Wu ; h_new = nmask ? tanh(u) : hid
    float2 nh = make_float2(0.f, 0.f);
    if (act) {
        const float2* Wu2 = (const float2*)Wu;
        float u0 = 0.f, u1 = 0.f;
        const float* hr = hid_s + v * H_;
        const float* mr = msg_s + v * H_;
#pragma unroll 4
        for (int k = 0; k < H_; ++k) {
            const float hk = hr[k];
            const float2 wu = Wu2[k * 50 + hp];
            u0 = fmaf(hk, wu.x, u0); u1 = fmaf(hk, wu.y, u1);
        }
#pragma unroll 4
        for (int k = 0; k < H_; ++k) {
            const float mk = mr[k];
            const float2 wu = Wu2[(H_ + k) * 50 + hp];
            u0 = fmaf(mk, wu.x, u0); u1 = fmaf(mk, wu.y, u1);
        }
        const float nm = nmask[row];
        nh.x = (nm != 0.f) ? tanhf(u0) : hr[hp * 2];
        nh.y = (nm != 0.f) ? tanhf(u1) : hr[hp * 2 + 1];
        *(float2*)(hidden + (size_t)row * H_ + hp * 2) = nh;
        if (do_proj) *(float2*)(hnew_s + v * H_ + hp * 2) = nh;
    }

    if (do_proj) {      // next pass's hv/hw from fresh hidden (own rows)
        __syncthreads();
        if (act) {
            const float2* Wv2 = (const float2*)Wv;
            const float2* Ww2 = (const float2*)Ww;
            float va0 = 0, va1 = 0, wa0 = 0, wa1 = 0;
            const float* hr = hnew_s + v * H_;
#pragma unroll 4
            for (int k = 0; k < H_; ++k) {
                const float hk = hr[k];
                const float2 wv = Wv2[k * 50 + hp];
                const float2 ww = Ww2[k * 50 + hp];
                va0 = fmaf(hk, wv.x, va0); va1 = fmaf(hk, wv.y, va1);
                wa0 = fmaf(hk, ww.x, wa0); wa1 = fmaf(hk, ww.y, wa1);
            }
            *(float2*)(hv_io + (size_t)row * H_ + hp * 2) = make_float2(va0, va1);
            *(float2*)(hw_out + (size_t)row * H_ + hp * 2) = make_float2(wa0, wa1);
        }
    }
}

// ---------------------------------------------------------------------------
// K3: readout. graph_terms = relu([hidden, nodes] @ Wr), masked sum over v.
__global__ __launch_bounds__(TPB) void k_readout(const float* __restrict__ hidden,
                                                 const float* __restrict__ nodes,
                                                 const float* __restrict__ Wr,
                                                 const float* __restrict__ nmask,
                                                 float* __restrict__ out) {
    __shared__ float hid_s[VT * H_], nod_s[VT * H_], red_s[VT * H_];
    const int b = blockIdx.y, v0 = blockIdx.x * VT;
    const int t = threadIdx.x, v = t / 50, hp = t % 50;
    const bool act = (v < VT);
    const int row = b * N_ + v0 + (act ? v : 0);

    const float4* hg = (const float4*)(hidden + (size_t)(b * N_ + v0) * H_);
    const float4* ng = (const float4*)(nodes + (size_t)(b * N_ + v0) * H_);
    for (int idx = t; idx < VT * 25; idx += TPB) ((float4*)hid_s)[idx] = hg[idx];
    for (int idx = t; idx < VT * 25; idx += TPB) ((float4*)nod_s)[idx] = ng[idx];
    __syncthreads();

    if (act) {
        const float2* Wr2 = (const float2*)Wr;
        float u0 = 0.f, u1 = 0.f;
        const float* hr = hid_s + v * H_;
        const float* nr = nod_s + v * H_;
#pragma unroll 4
        for (int k = 0; k < H_; ++k) {
            const float hk = hr[k];
            const float2 wr = Wr2[k * 50 + hp];
            u0 = fmaf(hk, wr.x, u0); u1 = fmaf(hk, wr.y, u1);
        }
#pragma unroll 4
        for (int k = 0; k < H_; ++k) {
            const float nk = nr[k];
            const float2 wr = Wr2[(H_ + k) * 50 + hp];
            u0 = fmaf(nk, wr.x, u0); u1 = fmaf(nk, wr.y, u1);
        }
        const float m = nmask[row];
        red_s[v * H_ + hp * 2]     = m * fmaxf(u0, 0.f);
        red_s[v * H_ + hp * 2 + 1] = m * fmaxf(u1, 0.f);
    }
    __syncthreads();
    if (t < H_) {
        float s = 0.f;
#pragma unroll
        for (int vv = 0; vv < VT; ++vv) s += red_s[vv * H_ + t];
        atomicAdd(out + b * H_ + t, s);
    }
}

// ---------------------------------------------------------------------------
extern "C" void kernel_launch(void* const* d_in, const int* in_sizes, int n_in,
                              void* d_out, int out_size, void* d_ws, size_t ws_size,
                              hipStream_t stream) {
    const float* nodes = (const float*)d_in[0];
    const float* edges = (const float*)d_in[1];
    const float* Wv    = (const float*)d_in[2];
    const float* Ww    = (const float*)d_in[3];
    const float* We    = (const float*)d_in[4];
    const float* Wu    = (const float*)d_in[5];
    const float* Wr    = (const float*)d_in[6];
    float* out = (float*)d_out;

    const size_t RH = (size_t)ROWS * H_;
    float* hidden = (float*)d_ws;        // RH
    float* hv     = hidden + RH;         // RH (block-private across passes)
    float* hwA    = hv + RH;             // RH
    float* hwB    = hwA + RH;            // RH
    float* nmask  = hwB + RH;            // ROWS
    float* maskf  = nmask + ROWS;        // ROWS * N_

    hipMemsetAsync(d_out, 0, (size_t)out_size * sizeof(float), stream);

    const dim3 grid(N_ / VT, B_);        // (32, 32) = 1024 blocks -> 4/CU
    k_mask<<<ROWS / 4, 256, 0, stream>>>(edges, maskf, nmask);
    k_proj0<<<grid, TPB, 0, stream>>>(nodes, Wv, Ww, hv, hwA);
    // pass 0 reads hid from nodes, writes hidden
    k_pass<<<grid, TPB, 0, stream>>>(edges, maskf, Wv, Ww, We, Wu, hv, hwA, hwB, nodes,  hidden, nmask, 1);
    k_pass<<<grid, TPB, 0, stream>>>(edges, maskf, Wv, Ww, We, Wu, hv, hwB, hwA, hidden, hidden, nmask, 1);
    k_pass<<<grid, TPB, 0, stream>>>(edges, maskf, Wv, Ww, We, Wu, hv, hwA, hwB, hidden, hidden, nmask, 0);
    k_readout<<<grid, TPB, 0, stream>>>(hidden, nodes, Wr, nmask, out);
}